// Round 2
// baseline (35.283 us; speedup 1.0000x reference)
//
#include <hip/hip_runtime.h>

#define IMG_H 720
#define IMG_W 1280
#define IMG_N 2
#define PADH (IMG_H + 6)   // 726
#define PADW 1296          // 1280 + 6, rounded up to multiple of 16 floats
// pixel (y,x) lives at padded (y+3, x+3); borders are zero.

// -50 * log2(e): color term in exp2 domain
#define C2 (-72.13475204444817f)
// log2(e)/50: spatial term scale in exp2 domain
#define S2SCALE (0.028853900817779268f)

#if defined(__has_builtin)
#if __has_builtin(__builtin_amdgcn_exp2f)
#define EXP2(x) __builtin_amdgcn_exp2f(x)
#else
#define EXP2(x) exp2f(x)
#endif
#else
#define EXP2(x) exp2f(x)
#endif

__global__ __launch_bounds__(256) void pad_kernel(
    const float* __restrict__ I, float* __restrict__ P) {
    int idx = blockIdx.x * blockDim.x + threadIdx.x;
    const int total = IMG_N * PADH * PADW;
    if (idx >= total) return;
    int x = idx % PADW;
    int y = (idx / PADW) % PADH;
    int n = idx / (PADW * PADH);
    int sx = x - 3, sy = y - 3;
    float v = 0.0f;
    if (sx >= 0 && sx < IMG_W && sy >= 0 && sy < IMG_H)
        v = I[(n * IMG_H + sy) * IMG_W + sx];
    P[idx] = v;
}

__device__ __forceinline__ void do_row(const float* __restrict__ rowptr,
                                       const float c[4], float acc_w[4],
                                       float acc_iw[4], float ry2) {
    float4 a = *(const float4*)(rowptr);
    float4 b = *(const float4*)(rowptr + 4);
    float4 d4 = *(const float4*)(rowptr + 8);
    float f[12] = {a.x, a.y, a.z, a.w, b.x, b.y, b.z, b.w,
                   d4.x, d4.y, d4.z, d4.w};
#pragma unroll
    for (int p = 0; p < 4; ++p) {
#pragma unroll
        for (int dx = 0; dx < 7; ++dx) {
            float v = f[p + dx];
            // exponent (log2 domain): C2*d^2 - (ry2+rx2)*S2SCALE
            float s2 = -(ry2 + (float)((dx - 3) * (dx - 3))) * S2SCALE;
            float dd = v - c[p];
            float e = fmaf(dd * dd, C2, s2);
            float w = EXP2(e);
            acc_w[p] += w;
            acc_iw[p] = fmaf(w, v, acc_iw[p]);
        }
    }
}

__global__ __launch_bounds__(256) void bilateral_main(
    const float* __restrict__ P, float* __restrict__ O) {
    int gid = blockIdx.x * blockDim.x + threadIdx.x;
    const int QPR = IMG_W / 4;  // 320 quads per row
    const int total = IMG_N * IMG_H * QPR;
    if (gid >= total) return;
    int q = gid % QPR;
    int y = (gid / QPR) % IMG_H;
    int n = gid / (QPR * IMG_H);
    int x0 = q * 4;

    // output px (y, x0+p): needs padded rows y..y+6, padded cols x0..x0+9
    const float* base = P + ((size_t)n * PADH + y) * PADW + x0;

    float c[4];
#pragma unroll
    for (int p = 0; p < 4; ++p) c[p] = base[3 * PADW + 3 + p];

    float acc_w[4] = {0.f, 0.f, 0.f, 0.f};
    float acc_iw[4] = {0.f, 0.f, 0.f, 0.f};

    do_row(base + 0 * PADW, c, acc_w, acc_iw, 9.0f);
    do_row(base + 1 * PADW, c, acc_w, acc_iw, 4.0f);
    do_row(base + 2 * PADW, c, acc_w, acc_iw, 1.0f);
    do_row(base + 3 * PADW, c, acc_w, acc_iw, 0.0f);
    do_row(base + 4 * PADW, c, acc_w, acc_iw, 1.0f);
    do_row(base + 5 * PADW, c, acc_w, acc_iw, 4.0f);
    do_row(base + 6 * PADW, c, acc_w, acc_iw, 9.0f);

    float* out = O + ((size_t)n * IMG_H + y) * IMG_W + x0;
    float4 r;
    r.x = acc_iw[0] / acc_w[0];
    r.y = acc_iw[1] / acc_w[1];
    r.z = acc_iw[2] / acc_w[2];
    r.w = acc_iw[3] / acc_w[3];
    *(float4*)out = r;
}

// ---------------- fallback (ws too small): round-0 kernel ----------------
__global__ __launch_bounds__(256) void bilateral_fallback(
    const float* __restrict__ I, float* __restrict__ O) {
    int idx = blockIdx.x * blockDim.x + threadIdx.x;
    const int total = IMG_N * IMG_H * IMG_W;
    if (idx >= total) return;
    int x = idx % IMG_W;
    int y = (idx / IMG_W) % IMG_H;
    int n = idx / (IMG_W * IMG_H);
    const float* img = I + n * (IMG_H * IMG_W);
    float cc = img[y * IMG_W + x];
    float wsum = 0.0f, iwsum = 0.0f;
#pragma unroll
    for (int dy = -3; dy <= 3; ++dy) {
        int yy = y + dy;
        bool yok = (yy >= 0) && (yy < IMG_H);
        const float* row = img + yy * IMG_W;
#pragma unroll
        for (int dx = -3; dx <= 3; ++dx) {
            int xx = x + dx;
            const float spatial = -(float)(dy * dy + dx * dx) / 50.0f;
            float v = 0.0f;
            if (yok && xx >= 0 && xx < IMG_W) v = row[xx];
            float d = v - cc;
            float e = fmaf(d * d, -50.0f, spatial);
            float w = __expf(e);
            wsum += w;
            iwsum = fmaf(w, v, iwsum);
        }
    }
    O[idx] = iwsum / wsum;
}

extern "C" void kernel_launch(void* const* d_in, const int* in_sizes, int n_in,
                              void* d_out, int out_size, void* d_ws, size_t ws_size,
                              hipStream_t stream) {
    const float* I = (const float*)d_in[0];
    float* O = (float*)d_out;

    const size_t need = (size_t)IMG_N * PADH * PADW * sizeof(float);
    if (ws_size >= need && d_ws != nullptr) {
        float* P = (float*)d_ws;
        {
            const int total = IMG_N * PADH * PADW;
            pad_kernel<<<(total + 255) / 256, 256, 0, stream>>>(I, P);
        }
        {
            const int total = IMG_N * IMG_H * (IMG_W / 4);
            bilateral_main<<<(total + 255) / 256, 256, 0, stream>>>(P, O);
        }
    } else {
        const int total = IMG_N * IMG_H * IMG_W;
        bilateral_fallback<<<(total + 255) / 256, 256, 0, stream>>>(I, O);
    }
}

// Round 3
// 27.326 us; speedup vs baseline: 1.2912x; 1.2912x over previous
//
#include <hip/hip_runtime.h>

#define IMG_H 720
#define IMG_W 1280
#define IMG_N 2

#define TX 64          // output tile width
#define TY 16          // output tile height
#define NBX (IMG_W / TX)   // 20
#define NBY (IMG_H / TY)   // 45
#define LW 72          // LDS row stride (70 used); 72 words % 32 banks = 8
#define LH (TY + 6)    // 22

// -50 * log2(e): color term in exp2 domain
#define C2 (-72.13475204444817f)
// 1/(50*ln2): spatial scale in exp2 domain (exp(-r2/50) = exp2(-r2*S2))
#define S2SCALE (0.028853900817779268f)

#if defined(__has_builtin)
#if __has_builtin(__builtin_amdgcn_exp2f)
#define EXP2(x) __builtin_amdgcn_exp2f(x)
#else
#define EXP2(x) exp2f(x)
#endif
#if __has_builtin(__builtin_amdgcn_rcpf)
#define RCP(x) __builtin_amdgcn_rcpf(x)
#else
#define RCP(x) (1.0f / (x))
#endif
#else
#define EXP2(x) exp2f(x)
#define RCP(x) (1.0f / (x))
#endif

__global__ __launch_bounds__(256) void bilateral_tile(
    const float* __restrict__ I, float* __restrict__ O) {
    int b = blockIdx.x;
    int bx = b % NBX;
    int by = (b / NBX) % NBY;
    int n = b / (NBX * NBY);
    int tx0 = bx * TX, ty0 = by * TY;

    __shared__ float S[LH][LW];
    const float* img = I + (size_t)n * IMG_H * IMG_W;
    int tid = threadIdx.x;

    // Stage (TY+6) x 70 window (zero-padded at image borders) into LDS.
#pragma unroll
    for (int i = 0; i < 7; ++i) {
        int idx = tid + i * 256;
        if (idx < LH * LW) {
            int r = idx / LW, col = idx % LW;
            int gy = ty0 - 3 + r, gx = tx0 - 3 + col;
            float v = 0.0f;
            if (col < 70 && gy >= 0 && gy < IMG_H && gx >= 0 && gx < IMG_W)
                v = img[gy * IMG_W + gx];
            S[r][col] = v;
        }
    }
    __syncthreads();

    // Each thread: 4 consecutive output pixels in x.
    int px = tid & 15;        // quad index in tile row: 0..15
    int py = tid >> 4;        // tile row: 0..15
    int x0 = px * 4;

    // keep C2 in a register so fma can use (vgpr, vgpr, sgpr) legally
    float c2v = C2;

    float c[4];
#pragma unroll
    for (int p = 0; p < 4; ++p) c[p] = S[py + 3][x0 + 3 + p];

    float acc_w[4] = {0.f, 0.f, 0.f, 0.f};
    float acc_iw[4] = {0.f, 0.f, 0.f, 0.f};

#pragma unroll
    for (int r = 0; r < 7; ++r) {
        const float* row = &S[py + r][x0];
        float4 a = *(const float4*)(row);
        float4 bb = *(const float4*)(row + 4);
        float4 d4 = *(const float4*)(row + 8);
        float f[12] = {a.x, a.y, a.z, a.w, bb.x, bb.y, bb.z, bb.w,
                       d4.x, d4.y, d4.z, d4.w};
        const int ry2 = (r - 3) * (r - 3);
#pragma unroll
        for (int p = 0; p < 4; ++p) {
#pragma unroll
            for (int dx = 0; dx < 7; ++dx) {
                float v = f[p + dx];
                const float s2 = -(float)(ry2 + (dx - 3) * (dx - 3)) * S2SCALE;
                float dd = v - c[p];
                float e = fmaf(dd * dd, c2v, s2);
                float w = EXP2(e);
                acc_w[p] += w;
                acc_iw[p] = fmaf(w, v, acc_iw[p]);
            }
        }
    }

    float* out = O + ((size_t)n * IMG_H + (ty0 + py)) * IMG_W + tx0 + x0;
    float4 rr;
    rr.x = acc_iw[0] * RCP(acc_w[0]);
    rr.y = acc_iw[1] * RCP(acc_w[1]);
    rr.z = acc_iw[2] * RCP(acc_w[2]);
    rr.w = acc_iw[3] * RCP(acc_w[3]);
    *(float4*)out = rr;
}

extern "C" void kernel_launch(void* const* d_in, const int* in_sizes, int n_in,
                              void* d_out, int out_size, void* d_ws, size_t ws_size,
                              hipStream_t stream) {
    const float* I = (const float*)d_in[0];
    float* O = (float*)d_out;
    const int blocks = IMG_N * NBX * NBY;  // 1800
    bilateral_tile<<<blocks, 256, 0, stream>>>(I, O);
}